// Round 1
// 2189.819 us; speedup vs baseline: 1.4415x; 1.4415x over previous
//
#include <hip/hip_runtime.h>
#include <hip/hip_bf16.h>
#include <cstdint>
#include <cstddef>

typedef unsigned short u16;
typedef short s8v __attribute__((ext_vector_type(8)));
typedef float f4v __attribute__((ext_vector_type(4)));

#define DI __device__ __forceinline__

// ---------- helpers ----------
DI u16 f2bf(float f){ unsigned u = __float_as_uint(f); u += 0x7fffu + ((u>>16)&1u); return (u16)(u>>16); }
DI float bf2f(u16 h){ return __uint_as_float(((unsigned)h)<<16); }
DI int ocol(int pc){ return ((pc>>3)&3)*512 + (pc>>5)*8 + (pc&7); }  // packed col -> original col
// slot layout (gate-contiguous): slot s = hb*32 + jj*4 + g  ->  original col
DI int ocol2(int s){ int pc = (s & ~31) | ((s&3)<<3) | ((s>>2)&7); return ocol(pc); }
DI float sigm(float x){ x = fminf(fmaxf(x,-30.f),30.f); return 1.f/(1.f+__expf(-x)); }
DI float tanhx(float x){ x = fminf(fmaxf(x,-15.f),15.f); float e = __expf(-2.f*x); return (1.f-e)/(1.f+e); }
DI uint4 packh8(const u16* h){
  uint4 r; r.x=(unsigned)h[0]|((unsigned)h[1]<<16); r.y=(unsigned)h[2]|((unsigned)h[3]<<16);
  r.z=(unsigned)h[4]|((unsigned)h[5]<<16); r.w=(unsigned)h[6]|((unsigned)h[7]<<16); return r;
}
DI void unp8(uint4 w, float* o){
  o[0]=bf2f((u16)(w.x&0xffffu)); o[1]=bf2f((u16)(w.x>>16));
  o[2]=bf2f((u16)(w.y&0xffffu)); o[3]=bf2f((u16)(w.y>>16));
  o[4]=bf2f((u16)(w.z&0xffffu)); o[5]=bf2f((u16)(w.z>>16));
  o[6]=bf2f((u16)(w.w&0xffffu)); o[7]=bf2f((u16)(w.w>>16));
}
DI s8v u4s8(uint4 u){ union{uint4 a; s8v b;} t; t.a=u; return t.b; }

// ---------- small builder kernels ----------
__global__ void k_init(const float* bb, const float* eh, const float* ec,
                       float* bp, float* h2X, float* cst, float* ctxX){
  int i = blockIdx.x*256 + threadIdx.x;
  if (i < 2048) bp[i] = bb[ocol2(i)];
  else if (i < 2048+32768) h2X[i-2048] = eh[i-2048];
  else if (i < 2048+65536) cst[i-34816] = ec[i-34816];
  else if (i < 2048+131072) ctxX[i-67584] = 0.f;
}

// hcat = [h0 | zeros] as bf16 hi/lo split, rows b, 1536 cols
__global__ void k_hinit(const float* __restrict__ eh, u16* __restrict__ hhi, u16* __restrict__ hlo){
  int i = blockIdx.x*256 + threadIdx.x; if (i >= 64*1536) return;
  int c = i % 1536;
  float f = (c < 512) ? eh[(i/1536)*512 + c] : 0.f;
  u16 hi = f2bf(f);
  hhi[i] = hi;
  hlo[i] = (c < 512) ? f2bf(f - bf2f(hi)) : (u16)0;
}

__global__ void k_cvt(const float* __restrict__ src, u16* __restrict__ dst, int octs){
  int g = blockIdx.x*256 + threadIdx.x; if (g >= octs) return;
  const float4* p = (const float4*)(src + (size_t)g*8);
  float4 a = p[0], b = p[1];
  u16 h[8] = {f2bf(a.x),f2bf(a.y),f2bf(a.z),f2bf(a.w),f2bf(b.x),f2bf(b.y),f2bf(b.z),f2bf(b.w)};
  *(uint4*)&dst[(size_t)g*8] = packh8(h);
}

__global__ void k_embgather(const int* __restrict__ dec, const float* __restrict__ emb, u16* __restrict__ dst){
  int g = blockIdx.x*256 + threadIdx.x; if (g >= 3776*40) return;
  int row = g/40, o = g%40;
  int b = row & 63, t = row >> 6;
  int tok = dec[b*59 + t];
  u16 h[8];
  #pragma unroll
  for(int j=0;j<8;++j){ int k = o*8+j; float f = (k<300)? emb[(size_t)tok*300 + k] : 0.f; h[j]=f2bf(f); }
  *(uint4*)&dst[(size_t)row*320 + o*8] = packh8(h);
}

__global__ void k_wmT(const float* __restrict__ Wm, u16* __restrict__ dst){
  int g = blockIdx.x*256 + threadIdx.x; if (g >= 512*128) return;
  int hcol = g/128, o = g%128;
  u16 h[8];
  #pragma unroll
  for(int j=0;j<8;++j){ int m = o*8+j; h[j]=f2bf(Wm[(size_t)m*512 + hcol]); }
  *(uint4*)&dst[(size_t)hcol*1024 + o*8] = packh8(h);
}

__global__ void k_waT(const float* __restrict__ Wa, u16* __restrict__ dst){
  int g = blockIdx.x*256 + threadIdx.x; if (g >= 512*192) return;
  int c = g/192, o = g%192;
  u16 h[8];
  #pragma unroll
  for(int j=0;j<8;++j){ int k = o*8+j; h[j]=f2bf(Wa[(size_t)k*512 + c]); }
  *(uint4*)&dst[(size_t)c*1536 + o*8] = packh8(h);
}

// Wx top rows (emb part), cols in slot (gate-contiguous) order -> Zemb lands gate-contiguous
__global__ void k_wxtpT(const float* __restrict__ Wx, u16* __restrict__ dst){
  int g = blockIdx.x*256 + threadIdx.x; if (g >= 2048*40) return;
  int pc = g/40, o = g%40; int oc = ocol2(pc);
  u16 h[8];
  #pragma unroll
  for(int j=0;j<8;++j){ int e = o*8+j; float f = (e<300)? Wx[(size_t)e*2048 + oc] : 0.f; h[j]=f2bf(f); }
  *(uint4*)&dst[(size_t)pc*320 + o*8] = packh8(h);
}

// Wx_att^T splits: segs [hi(512) | hi(512) | lo(512)] along k'  (packed-pc cols)
__global__ void k_wxaT(const float* __restrict__ Wx, u16* __restrict__ dst){
  int g = blockIdx.x*256 + threadIdx.x; if (g >= 2048*192) return;
  int pc = g/192, o = g%192; int oc = ocol(pc);
  u16 h[8];
  #pragma unroll
  for(int j=0;j<8;++j){
    int kp = o*8+j; int seg = kp>>9; int jd = kp&511;
    float f = Wx[(size_t)(300+jd)*2048 + oc];
    u16 hi = f2bf(f);
    h[j] = (seg==2) ? f2bf(f - bf2f(hi)) : hi;
  }
  *(uint4*)&dst[(size_t)pc*1536 + o*8] = packh8(h);
}

// Wa splits (A side of composite GEMM): segs [hi | lo | hi]
__global__ void k_waA(const float* __restrict__ Wa, u16* __restrict__ dst){
  int g = blockIdx.x*256 + threadIdx.x; if (g >= 1536*192) return;
  int r = g/192, o = g%192;
  u16 h[8];
  #pragma unroll
  for(int j=0;j<8;++j){
    int kp = o*8+j; int seg = kp>>9; int jd = kp&511;
    float f = Wa[(size_t)r*512 + jd];
    u16 hi = f2bf(f);
    h[j] = (seg==1) ? f2bf(f - bf2f(hi)) : hi;
  }
  *(uint4*)&dst[(size_t)r*1536 + o*8] = packh8(h);
}

// Uh^T packed splits: phys [hi(512) | lo(512)]
__global__ void k_buhT(const float* __restrict__ Uh, u16* __restrict__ dst){
  int g = blockIdx.x*256 + threadIdx.x; if (g >= 2048*128) return;
  int pc = g/128, o = g%128; int oc = ocol(pc);
  u16 h[8];
  #pragma unroll
  for(int j=0;j<8;++j){
    int kp = o*8+j; int r = kp&511;
    float f = Uh[(size_t)r*2048 + oc];
    u16 hi = f2bf(f);
    h[j] = (kp<512) ? hi : f2bf(f - bf2f(hi));
  }
  *(uint4*)&dst[(size_t)pc*1024 + o*8] = packh8(h);
}

// (Wzc + Uh-on-top)^T splits: phys [hi(1536) | lo(1536)]
__global__ void k_wzcT(const float* __restrict__ wzc, const float* __restrict__ Uh, u16* __restrict__ dst){
  int g = blockIdx.x*256 + threadIdx.x; if (g >= 2048*384) return;
  int pc = g/384, o = g%384; int oc = ocol(pc);
  u16 h[8];
  #pragma unroll
  for(int j=0;j<8;++j){
    int kp = o*8+j; int r = kp % 1536;
    float f = wzc[(size_t)r*2048 + pc] + ((r<512) ? Uh[(size_t)r*2048 + oc] : 0.f);
    u16 hi = f2bf(f);
    h[j] = (kp<1536) ? hi : f2bf(f - bf2f(hi));
  }
  *(uint4*)&dst[(size_t)pc*3072 + o*8] = packh8(h);
}

// A2cat = [h2 | ctx] bf16, rows r = t*64+b  (reads slot t+1 == row r+64)
__global__ void k_a2dump(const float* __restrict__ h2X, const float* __restrict__ ctxX, u16* __restrict__ dst){
  int g = blockIdx.x*256 + threadIdx.x; if (g >= 3776*192) return;
  int r = g/192, o = g%192;
  u16 h[8];
  #pragma unroll
  for(int j=0;j<8;++j){
    int k = o*8+j;
    float f = (k<512) ? h2X[(size_t)(r+64)*512 + k] : ctxX[(size_t)(r+64)*1024 + (k-512)];
    h[j] = f2bf(f);
  }
  *(uint4*)&dst[(size_t)r*1536 + o*8] = packh8(h);
}

// Wf [512][34004] f32 -> WfT [34004][512] bf16 (LDS-tiled transpose)
__global__ __launch_bounds__(256) void k_wfT(const float* __restrict__ Wf, u16* __restrict__ WfT){
  __shared__ u16 T[64*72];
  int n0 = blockIdx.x*64, k0 = blockIdx.y*64;
  int tid = threadIdx.x;
  int kl = tid>>2, nq = (tid&3)*16;
  u16 h[16];
  if (n0 + 64 <= 34004){
    const float4* p = (const float4*)(Wf + (size_t)(k0+kl)*34004 + n0 + nq);
    #pragma unroll
    for(int q=0;q<4;++q){ float4 f = p[q]; h[q*4+0]=f2bf(f.x); h[q*4+1]=f2bf(f.y); h[q*4+2]=f2bf(f.z); h[q*4+3]=f2bf(f.w); }
  } else {
    #pragma unroll
    for(int j=0;j<16;++j){ int n = n0+nq+j; float f = (n<34004)? Wf[(size_t)(k0+kl)*34004 + n] : 0.f; h[j]=f2bf(f); }
  }
  *(uint4*)&T[kl*72 + nq] = packh8(h);
  *(uint4*)&T[kl*72 + nq + 8] = packh8(h+8);
  __syncthreads();
  int nl = tid>>2, kq = (tid&3)*16;
  int n = n0 + nl;
  if (n < 34004){
    u16 o[16];
    #pragma unroll
    for(int j=0;j<16;++j) o[j] = T[(kq+j)*72 + nl];
    *(uint4*)&WfT[(size_t)n*512 + k0 + kq]     = packh8(o);
    *(uint4*)&WfT[(size_t)n*512 + k0 + kq + 8] = packh8(o+8);
  }
}

// ---------- generic 128x128 bf16 MFMA GEMM:  C[M,N] = A[M,K] * Bt[N,K]^T ----------
// EPI: 0 plain f32, 1 +bias f32, 2 bf16 out, 3 logits (bias + (t,b)->(b,t) permuted store)
// Epilogue stages each wave's 16x64 sub-tile through LDS and stores lane-contiguous
// float4 (256B per 16 lanes) -> full-line writes, no write-allocate RMW on HBM.
template<int EPI>
__global__ __launch_bounds__(256,2) void gemm_bf16(
    const u16* __restrict__ A, const u16* __restrict__ Bt,
    int M, int N, int K,
    float* __restrict__ Cf, u16* __restrict__ Cb,
    const float* __restrict__ bias, float* __restrict__ Cout){
  __shared__ u16 LSbuf[2*128*40];
  u16* Als = LSbuf;
  u16* Bls = LSbuf + 128*40;
  int tid = threadIdx.x;
  int c0 = blockIdx.x*128, r0 = blockIdx.y*128;
  int wid = tid>>6, wr = wid>>1, wc = wid&1;
  int l15 = tid&15, l4 = (tid>>4)&3;
  f4v acc[4][4];
  #pragma unroll
  for(int m=0;m<4;++m)
  #pragma unroll
  for(int n=0;n<4;++n)
  #pragma unroll
  for(int i=0;i<4;++i) acc[m][n][i] = 0.f;

  int r = tid>>1, hf = tid&1;
  size_t arow = (size_t)min(r0 + r, M-1);
  size_t brow = (size_t)min(c0 + r, N-1);
  int nk = K >> 5;
  for (int ch=0; ch<nk; ++ch){
    int k0 = ch*32;
    const uint4* ap = (const uint4*)(A  + arow*K + k0 + hf*16);
    const uint4* bp = (const uint4*)(Bt + brow*K + k0 + hf*16);
    uint4 a0 = ap[0], a1 = ap[1];
    uint4 b0 = bp[0], b1 = bp[1];
    __syncthreads();
    *(uint4*)&Als[r*40 + hf*16]     = a0;
    *(uint4*)&Als[r*40 + hf*16 + 8] = a1;
    *(uint4*)&Bls[r*40 + hf*16]     = b0;
    *(uint4*)&Bls[r*40 + hf*16 + 8] = b1;
    __syncthreads();
    s8v af[4], bfr[4];
    #pragma unroll
    for(int m=0;m<4;++m) af[m]  = *(const s8v*)&Als[(wr*64 + m*16 + l15)*40 + l4*8];
    #pragma unroll
    for(int n=0;n<4;++n) bfr[n] = *(const s8v*)&Bls[(wc*64 + n*16 + l15)*40 + l4*8];
    #pragma unroll
    for(int m=0;m<4;++m)
    #pragma unroll
    for(int n=0;n<4;++n)
      acc[m][n] = __builtin_amdgcn_mfma_f32_16x16x32_bf16(af[m], bfr[n], acc[m][n], 0,0,0);
  }
  // epilogue: LDS-staged transpose to full-line float4 stores
  __syncthreads();   // all waves done reading Als/Bls before reuse
  float* eps = ((float*)LSbuf) + wid*1024;   // 16 rows x 64 cols per wave
  #pragma unroll
  for(int m=0;m<4;++m){
    #pragma unroll
    for(int n=0;n<4;++n)
    #pragma unroll
    for(int i=0;i<4;++i)
      eps[(l4*4 + i)*64 + n*16 + l15] = acc[m][n][i];
    // per-wave region: in-order LDS ops within a wave, no __syncthreads needed
    #pragma unroll
    for(int q=0;q<4;++q){
      int row = l4 + q*4;
      f4v v = *(const f4v*)&eps[row*64 + l15*4];
      int gr = r0 + wr*64 + m*16 + row;
      int gc = c0 + wc*64 + l15*4;
      if (gr < M && gc < N){
        if constexpr (EPI==0){
          *(f4v*)&Cf[(size_t)gr*N + gc] = v;
        } else if constexpr (EPI==1){
          f4v bv = *(const f4v*)&bias[gc];
          v += bv;
          *(f4v*)&Cf[(size_t)gr*N + gc] = v;
        } else if constexpr (EPI==2){
          unsigned p0 = ((unsigned)f2bf(v[1])<<16) | f2bf(v[0]);
          unsigned p1 = ((unsigned)f2bf(v[3])<<16) | f2bf(v[2]);
          uint2 pk; pk.x = p0; pk.y = p1;
          *(uint2*)&Cb[(size_t)gr*N + gc] = pk;
        } else {
          f4v bv = *(const f4v*)&bias[gc];
          v += bv;
          int b_ = gr&63, tt = gr>>6;
          *(f4v*)&Cout[((size_t)(b_*59 + tt))*34004 + gc] = v;
        }
      }
    }
  }
}

// ---------- per-step z-GEMM: 4 waves/block, each wave a 128-K sub-slice; LDS reduce ----------
// A comes pre-split as bf16 hi/lo hcat[64][1536] (h:0..511, ctx:512..1535).
// variant 0 (t==0): virtual K=1536 over h only [Ahi*Bhi | Alo*Bhi | Ahi*Blo], Bt=buhT physK=1024
// variant 1 (t>=1): virtual K=4608 [hi*hi | lo*hi | hi*lo] over 1536,     Bt=wzT physK=3072
// Output store remaps packed col pc -> gate-contiguous slot for float4 LSTM reads.
struct SBuf { uint4 a[4]; uint4 b[4]; };

__global__ __launch_bounds__(256,2) void s1_zgemm(
    const u16* __restrict__ Bt, const u16* __restrict__ hhi, const u16* __restrict__ hlo,
    float* __restrict__ zparts, int physK, int variant){
  __shared__ float red[4][64*64];
  int tid = threadIdx.x;
  int wv = tid>>6, lane = tid&63;
  int l15 = lane&15, l4 = lane>>4;
  int pc0 = blockIdx.x*64;
  int kbase = blockIdx.y*512 + wv*128;
  f4v acc[4][4];
  #pragma unroll
  for(int m=0;m<4;++m)
  #pragma unroll
  for(int n=0;n<4;++n)
  #pragma unroll
  for(int i=0;i<4;++i) acc[m][n][i] = 0.f;

  SBuf B0, B1;
  auto loadc = [&](SBuf& bu, int ch){
    int k1 = kbase + ch*32;
    const u16* ap; int inner;
    if (variant==0){ inner = k1 & 511; ap = ((((k1>>9)&3)==1) ? hlo : hhi); }
    else { int sg = k1/1536; inner = k1 - sg*1536; ap = ((sg==1) ? hlo : hhi); }
    #pragma unroll
    for(int m=0;m<4;++m)
      bu.a[m] = *(const uint4*)(ap + (size_t)(m*16 + l15)*1536 + inner + l4*8);
    int kB = (variant==0) ? ((k1 < 1024) ? (k1 & 511) : (k1 - 512))
                          : ((k1 < 3072) ? (k1 % 1536) : (1536 + (k1 - 3072)));
    #pragma unroll
    for(int n=0;n<4;++n)
      bu.b[n] = *(const uint4*)(Bt + (size_t)(pc0 + n*16 + l15)*physK + kB + l4*8);
  };
  auto proc = [&](SBuf& bu){
    #pragma unroll
    for(int m=0;m<4;++m){
      s8v am = u4s8(bu.a[m]);
      #pragma unroll
      for(int n=0;n<4;++n)
        acc[m][n] = __builtin_amdgcn_mfma_f32_16x16x32_bf16(am, u4s8(bu.b[n]), acc[m][n], 0,0,0);
    }
  };

  loadc(B0, 0); loadc(B1, 1);
  proc(B0);     loadc(B0, 2);
  proc(B1);     loadc(B1, 3);
  proc(B0);
  proc(B1);

  #pragma unroll
  for(int m=0;m<4;++m)
  #pragma unroll
  for(int n=0;n<4;++n)
  #pragma unroll
  for(int i=0;i<4;++i)
    red[wv][(m*16 + l4*4 + i)*64 + n*16 + l15] = acc[m][n][i];
  __syncthreads();

  int rr = tid>>2, cq = (tid&3)*16;
  float* zp = zparts + (size_t)blockIdx.y*131072 + (size_t)rr*2048;
  #pragma unroll
  for(int k=0;k<4;++k){
    f4v s = *(const f4v*)&red[0][rr*64 + cq + k*4];
    #pragma unroll
    for(int w=1;w<4;++w)
      s += *(const f4v*)&red[w][rr*64 + cq + k*4];
    #pragma unroll
    for(int e=0;e<4;++e){
      int pc = pc0 + cq + k*4 + e;
      int slot = (pc & ~31) | ((pc&7)<<2) | ((pc>>3)&3);
      zp[slot] = s[e];
    }
  }
}

// ---------- per-step fused: LSTM + q + scores/softmax + ctx  (one block per batch b) ----------
__global__ __launch_bounds__(512) void s2b_fused(
    const float* __restrict__ zparts, int nsl, const float* __restrict__ ZembT,
    float* __restrict__ cst, float* __restrict__ h2out, float* __restrict__ ctxout,
    const u16* __restrict__ Wqb, const float* __restrict__ keys,
    const float* __restrict__ enc, const float* __restrict__ vv,
    u16* __restrict__ hhi, u16* __restrict__ hlo){
  __shared__ float h2s[512], vs2[512], qs[512];
  __shared__ float qp_l[8*512];
  __shared__ float scl[32], all[32];
  int b = blockIdx.x, tid = threadIdx.x;

  // (a) LSTM for unit j = tid (gate-contiguous slot layout -> float4 loads)
  {
    int j = tid;
    int base = (j>>3)*32 + (j&7)*4;            // slots for gates i,f,g,o of unit j
    f4v s4 = *(const f4v*)&ZembT[(size_t)b*2048 + base];
    for(int sl=0; sl<nsl; ++sl)
      s4 += *(const f4v*)&zparts[(size_t)sl*131072 + (size_t)b*2048 + base];
    float cprev = cst[(size_t)b*512 + j];
    float c2 = sigm(s4[1])*cprev + sigm(s4[0])*tanhx(s4[2]);
    float h2 = sigm(s4[3])*tanhx(c2);
    cst[(size_t)b*512 + j] = c2;
    h2out[(size_t)b*512 + j] = h2;
    h2s[j] = h2; vs2[j] = vv[j];
    u16 hh = f2bf(h2);
    hhi[(size_t)b*1536 + j] = hh;
    hlo[(size_t)b*1536 + j] = f2bf(h2 - bf2f(hh));
  }
  __syncthreads();
  // (c) q = h2 @ Wq  (Wq kept natural [h][c], bf16): thread -> 8 cols, 1/8 of h
  {
    int c8 = (tid&63)*8, hs = tid>>6;
    float qp[8] = {0,0,0,0,0,0,0,0};
    for(int hh=0; hh<64; ++hh){
      int h = hs*64 + hh;
      float w[8]; unp8(*(const uint4*)(Wqb + (size_t)h*512 + c8), w);
      float hv = h2s[h];
      #pragma unroll
      for(int j=0;j<8;++j) qp[j] += hv*w[j];
    }
    *(float4*)&qp_l[hs*512 + c8]     = make_float4(qp[0],qp[1],qp[2],qp[3]);
    *(float4*)&qp_l[hs*512 + c8 + 4] = make_float4(qp[4],qp[5],qp[6],qp[7]);
  }
  __syncthreads();
  { float s = 0.f; for(int hs=0; hs<8; ++hs) s += qp_l[hs*512 + tid]; qs[tid] = s; }
  __syncthreads();
  // (e) scores[s] = sum_h v[h]*tanh(keys[b,s,h] + q[h]) ; 16 threads per s
  {
    int s = tid>>4, hh = tid&15;
    const float* kb = keys + ((size_t)(b*32 + s))*512;
    float part = 0.f;
    #pragma unroll 4
    for(int i=0;i<32;++i){
      int h = hh*32 + i;
      part += vs2[h]*tanhx(kb[h] + qs[h]);
    }
    #pragma unroll
    for(int m=1;m<16;m<<=1) part += __shfl_xor(part, m, 64);
    if (hh==0) scl[s] = part;
  }
  __syncthreads();
  // (g) softmax over 32
  if (tid < 32){
    float sc = scl[tid];
    float mx = sc;
    #pragma unroll
    for(int m=1;m<32;m<<=1) mx = fmaxf(mx, __shfl_xor(mx, m, 64));
    float e = __expf(sc - mx);
    float sm = e;
    #pragma unroll
    for(int m=1;m<32;m<<=1) sm += __shfl_xor(sm, m, 64);
    all[tid] = e/sm;
  }
  __syncthreads();
  // (i) ctx[m] = sum_s align[s]*enc[b,s,m] ; 2 cols per thread
  {
    const float* eb = enc + (size_t)b*32*1024;
    float c0 = 0.f, c1 = 0.f;
    for(int s=0;s<32;++s){
      float al = all[s];
      c0 += al*eb[(size_t)s*1024 + tid];
      c1 += al*eb[(size_t)s*1024 + tid + 512];
    }
    ctxout[(size_t)b*1024 + tid]       = c0;
    ctxout[(size_t)b*1024 + tid + 512] = c1;
    u16 x0 = f2bf(c0);
    hhi[(size_t)b*1536 + 512 + tid] = x0;
    hlo[(size_t)b*1536 + 512 + tid] = f2bf(c0 - bf2f(x0));
    u16 x1 = f2bf(c1);
    hhi[(size_t)b*1536 + 1024 + tid] = x1;
    hlo[(size_t)b*1536 + 1024 + tid] = f2bf(c1 - bf2f(x1));
  }
}

// ---------- host ----------
extern "C" void kernel_launch(void* const* d_in, const int* in_sizes, int n_in,
                              void* d_out, int out_size, void* d_ws, size_t ws_size,
                              hipStream_t stream){
  const int*   dec = (const int*)d_in[0];
  const float* enc = (const float*)d_in[1];
  const float* eh  = (const float*)d_in[2];
  const float* ec  = (const float*)d_in[3];
  const float* emb = (const float*)d_in[4];
  const float* Wx  = (const float*)d_in[5];
  const float* Uh  = (const float*)d_in[6];
  const float* bb  = (const float*)d_in[7];
  const float* Wm  = (const float*)d_in[8];
  const float* Wq  = (const float*)d_in[9];
  const float* vv  = (const float*)d_in[10];
  const float* Wa  = (const float*)d_in[11];
  const float* Wf  = (const float*)d_in[12];
  const float* bf  = (const float*)d_in[13];
  float* out = (float*)d_out;

  // ---- workspace carving ----
  char* w = (char*)d_ws; size_t off = 0;
  auto alloc = [&](size_t bytes)->char*{ char* p = w + off; off = (off + bytes + 255) & ~(size_t)255; return p; };
  // live-at-final-GEMM group (must be in ws):
  u16* WfT   = (u16*)alloc((size_t)34004*512*2);
  u16* attn2 = (u16*)alloc((size_t)3776*512*2);
  size_t liveEnd = off;
  const size_t needB = (size_t)130<<20;
  bool fits = (ws_size >= liveEnd + needB);
  char* wb = fits ? (w + liveEnd) : (char*)d_out;   // d_out region is dead until final GEMM writes it
  size_t offb = 0;
  auto allocB = [&](size_t bytes)->char*{ char* p = wb + offb; offb = (offb + bytes + 255) & ~(size_t)255; return p; };

  u16* wzT   = (u16*)allocB((size_t)2048*3072*2);
  u16* buhT  = (u16*)allocB((size_t)2048*1024*2);
  u16* wqB   = (u16*)allocB((size_t)512*512*2);
  u16* waT   = (u16*)allocB((size_t)512*1536*2);
  u16* wmT   = (u16*)allocB((size_t)512*1024*2);
  u16* wxtpT = (u16*)allocB((size_t)2048*320*2);
  u16* wxaT  = (u16*)allocB((size_t)2048*1536*2);
  u16* waA   = (u16*)allocB((size_t)1536*1536*2);
  float* wzc = (float*)allocB((size_t)1536*2048*4);
  u16* embB  = (u16*)allocB((size_t)3776*320*2);
  u16* encB  = (u16*)allocB((size_t)2048*1024*2);
  float* Zemb  = (float*)allocB((size_t)3776*2048*4);
  float* keys  = (float*)allocB((size_t)2048*512*4);
  float* zparts= (float*)allocB((size_t)9*64*2048*4);
  float* h2X   = (float*)allocB((size_t)60*64*512*4);
  float* ctxX  = (float*)allocB((size_t)60*64*1024*4);
  float* cst   = (float*)allocB((size_t)64*512*4);
  float* bp    = (float*)allocB((size_t)2048*4);
  u16* A2c   = (u16*)allocB((size_t)3776*1536*2);
  u16* hhi   = (u16*)allocB((size_t)64*1536*2);
  u16* hlo   = (u16*)allocB((size_t)64*1536*2);

  // ---- precompute ----
  k_init<<<520,256,0,stream>>>(bb, eh, ec, bp, h2X, cst, ctxX);
  k_hinit<<<384,256,0,stream>>>(eh, hhi, hlo);
  k_embgather<<<(3776*40+255)/256,256,0,stream>>>(dec, emb, embB);
  k_cvt<<<(262144+255)/256,256,0,stream>>>(enc, encB, 262144);          // enc -> bf16
  k_cvt<<<(32768+255)/256,256,0,stream>>>(Wq, wqB, 32768);              // Wq -> bf16 (natural layout)
  k_wmT<<<(512*128+255)/256,256,0,stream>>>(Wm, wmT);
  k_waT<<<(512*192+255)/256,256,0,stream>>>(Wa, waT);
  k_wxtpT<<<(2048*40+255)/256,256,0,stream>>>(Wx, wxtpT);
  k_wxaT<<<(2048*192+255)/256,256,0,stream>>>(Wx, wxaT);
  k_buhT<<<(2048*128+255)/256,256,0,stream>>>(Uh, buhT);
  k_waA<<<(1536*192+255)/256,256,0,stream>>>(Wa, waA);
  k_wfT<<<dim3(532,8),256,0,stream>>>(Wf, WfT);

  // Zemb = gather(emb) @ Wx_top (slot cols) + b   [3776][2048]
  gemm_bf16<1><<<dim3(16,30),256,0,stream>>>(embB, wxtpT, 3776, 2048, 320, Zemb, nullptr, bp, nullptr);
  // keys = enc @ Wm  [2048][512]
  gemm_bf16<0><<<dim3(4,16),256,0,stream>>>(encB, wmT, 2048, 512, 1024, keys, nullptr, nullptr, nullptr);
  // Wzc = Wa @ Wx_att (split-precision composite)  [1536][2048 packed]
  gemm_bf16<0><<<dim3(16,12),256,0,stream>>>(waA, wxaT, 1536, 2048, 1536, wzc, nullptr, nullptr, nullptr);
  // W'z^T = split( Wzc + Uh(top) )^T   [2048][3072]
  k_wzcT<<<(2048*384+255)/256,256,0,stream>>>(wzc, Uh, wzT);

  // ---- recurrence: 2 kernels per step ----
  for (int t=0; t<59; ++t){
    if (t==0){
      s1_zgemm<<<dim3(32,3),256,0,stream>>>(buhT, hhi, hlo, zparts, 1024, 0);
    } else {
      s1_zgemm<<<dim3(32,9),256,0,stream>>>(wzT, hhi, hlo, zparts, 3072, 1);
    }
    int nsl = (t==0) ? 3 : 9;
    s2b_fused<<<64,512,0,stream>>>(zparts, nsl, Zemb + (size_t)t*131072,
                                   cst, h2X + (size_t)(t+1)*32768, ctxX + (size_t)(t+1)*65536,
                                   wqB, keys, enc, vv, hhi, hlo);
  }

  // ---- deferred attn2 + logits ----
  k_a2dump<<<(3776*192+255)/256,256,0,stream>>>(h2X, ctxX, A2c);
  // attn2 = [h2|ctx] @ Wa  -> bf16 [3776][512]
  gemm_bf16<2><<<dim3(4,30),256,0,stream>>>(A2c, waT, 3776, 512, 1536, nullptr, attn2, nullptr, nullptr);
  // logits = attn2 @ Wf + bf, stored as out[b][t][v]
  gemm_bf16<3><<<dim3(266,30),256,0,stream>>>(attn2, WfT, 3776, 34004, 512, nullptr, nullptr, bf, out);
}

// Round 2
// 2184.655 us; speedup vs baseline: 1.4449x; 1.0024x over previous
//
#include <hip/hip_runtime.h>
#include <hip/hip_bf16.h>
#include <cstdint>
#include <cstddef>

typedef unsigned short u16;
typedef short s8v __attribute__((ext_vector_type(8)));
typedef float f4v __attribute__((ext_vector_type(4)));

#define DI __device__ __forceinline__

// ---------- helpers ----------
DI u16 f2bf(float f){ unsigned u = __float_as_uint(f); u += 0x7fffu + ((u>>16)&1u); return (u16)(u>>16); }
DI float bf2f(u16 h){ return __uint_as_float(((unsigned)h)<<16); }
DI int ocol(int pc){ return ((pc>>3)&3)*512 + (pc>>5)*8 + (pc&7); }  // packed col -> original col
// slot layout (gate-contiguous): slot s = hb*32 + jj*4 + g  ->  original col
DI int ocol2(int s){ int pc = (s & ~31) | ((s&3)<<3) | ((s>>2)&7); return ocol(pc); }
DI float sigm(float x){ x = fminf(fmaxf(x,-30.f),30.f); return 1.f/(1.f+__expf(-x)); }
DI float tanhx(float x){ x = fminf(fmaxf(x,-15.f),15.f); float e = __expf(-2.f*x); return (1.f-e)/(1.f+e); }
DI uint4 packh8(const u16* h){
  uint4 r; r.x=(unsigned)h[0]|((unsigned)h[1]<<16); r.y=(unsigned)h[2]|((unsigned)h[3]<<16);
  r.z=(unsigned)h[4]|((unsigned)h[5]<<16); r.w=(unsigned)h[6]|((unsigned)h[7]<<16); return r;
}
DI void unp8(uint4 w, float* o){
  o[0]=bf2f((u16)(w.x&0xffffu)); o[1]=bf2f((u16)(w.x>>16));
  o[2]=bf2f((u16)(w.y&0xffffu)); o[3]=bf2f((u16)(w.y>>16));
  o[4]=bf2f((u16)(w.z&0xffffu)); o[5]=bf2f((u16)(w.z>>16));
  o[6]=bf2f((u16)(w.w&0xffffu)); o[7]=bf2f((u16)(w.w>>16));
}
DI s8v u4s8(uint4 u){ union{uint4 a; s8v b;} t; t.a=u; return t.b; }

// ---------- small builder kernels ----------
__global__ void k_init(const float* bb, const float* eh, const float* ec,
                       float* bp, float* h2X, float* cst, float* ctxX){
  int i = blockIdx.x*256 + threadIdx.x;
  if (i < 2048) bp[i] = bb[ocol2(i)];
  else if (i < 2048+32768) h2X[i-2048] = eh[i-2048];
  else if (i < 2048+65536) cst[i-34816] = ec[i-34816];
  else if (i < 2048+131072) ctxX[i-67584] = 0.f;
}

// hcat = [h0 | zeros] as bf16 hi/lo split, rows b, 1536 cols
__global__ void k_hinit(const float* __restrict__ eh, u16* __restrict__ hhi, u16* __restrict__ hlo){
  int i = blockIdx.x*256 + threadIdx.x; if (i >= 64*1536) return;
  int c = i % 1536;
  float f = (c < 512) ? eh[(i/1536)*512 + c] : 0.f;
  u16 hi = f2bf(f);
  hhi[i] = hi;
  hlo[i] = (c < 512) ? f2bf(f - bf2f(hi)) : (u16)0;
}

__global__ void k_cvt(const float* __restrict__ src, u16* __restrict__ dst, int octs){
  int g = blockIdx.x*256 + threadIdx.x; if (g >= octs) return;
  const float4* p = (const float4*)(src + (size_t)g*8);
  float4 a = p[0], b = p[1];
  u16 h[8] = {f2bf(a.x),f2bf(a.y),f2bf(a.z),f2bf(a.w),f2bf(b.x),f2bf(b.y),f2bf(b.z),f2bf(b.w)};
  *(uint4*)&dst[(size_t)g*8] = packh8(h);
}

__global__ void k_embgather(const int* __restrict__ dec, const float* __restrict__ emb, u16* __restrict__ dst){
  int g = blockIdx.x*256 + threadIdx.x; if (g >= 3776*40) return;
  int row = g/40, o = g%40;
  int b = row & 63, t = row >> 6;
  int tok = dec[b*59 + t];
  u16 h[8];
  #pragma unroll
  for(int j=0;j<8;++j){ int k = o*8+j; float f = (k<300)? emb[(size_t)tok*300 + k] : 0.f; h[j]=f2bf(f); }
  *(uint4*)&dst[(size_t)row*320 + o*8] = packh8(h);
}

__global__ void k_wmT(const float* __restrict__ Wm, u16* __restrict__ dst){
  int g = blockIdx.x*256 + threadIdx.x; if (g >= 512*128) return;
  int hcol = g/128, o = g%128;
  u16 h[8];
  #pragma unroll
  for(int j=0;j<8;++j){ int m = o*8+j; h[j]=f2bf(Wm[(size_t)m*512 + hcol]); }
  *(uint4*)&dst[(size_t)hcol*1024 + o*8] = packh8(h);
}

__global__ void k_waT(const float* __restrict__ Wa, u16* __restrict__ dst){
  int g = blockIdx.x*256 + threadIdx.x; if (g >= 512*192) return;
  int c = g/192, o = g%192;
  u16 h[8];
  #pragma unroll
  for(int j=0;j<8;++j){ int k = o*8+j; h[j]=f2bf(Wa[(size_t)k*512 + c]); }
  *(uint4*)&dst[(size_t)c*1536 + o*8] = packh8(h);
}

// Wx top rows (emb part), cols in slot (gate-contiguous) order -> Zemb lands gate-contiguous
__global__ void k_wxtpT(const float* __restrict__ Wx, u16* __restrict__ dst){
  int g = blockIdx.x*256 + threadIdx.x; if (g >= 2048*40) return;
  int pc = g/40, o = g%40; int oc = ocol2(pc);
  u16 h[8];
  #pragma unroll
  for(int j=0;j<8;++j){ int e = o*8+j; float f = (e<300)? Wx[(size_t)e*2048 + oc] : 0.f; h[j]=f2bf(f); }
  *(uint4*)&dst[(size_t)pc*320 + o*8] = packh8(h);
}

// Wx_att^T splits: segs [hi(512) | hi(512) | lo(512)] along k'  (packed-pc cols)
__global__ void k_wxaT(const float* __restrict__ Wx, u16* __restrict__ dst){
  int g = blockIdx.x*256 + threadIdx.x; if (g >= 2048*192) return;
  int pc = g/192, o = g%192; int oc = ocol(pc);
  u16 h[8];
  #pragma unroll
  for(int j=0;j<8;++j){
    int kp = o*8+j; int seg = kp>>9; int jd = kp&511;
    float f = Wx[(size_t)(300+jd)*2048 + oc];
    u16 hi = f2bf(f);
    h[j] = (seg==2) ? f2bf(f - bf2f(hi)) : hi;
  }
  *(uint4*)&dst[(size_t)pc*1536 + o*8] = packh8(h);
}

// Wa splits (A side of composite GEMM): segs [hi | lo | hi]
__global__ void k_waA(const float* __restrict__ Wa, u16* __restrict__ dst){
  int g = blockIdx.x*256 + threadIdx.x; if (g >= 1536*192) return;
  int r = g/192, o = g%192;
  u16 h[8];
  #pragma unroll
  for(int j=0;j<8;++j){
    int kp = o*8+j; int seg = kp>>9; int jd = kp&511;
    float f = Wa[(size_t)r*512 + jd];
    u16 hi = f2bf(f);
    h[j] = (seg==1) ? f2bf(f - bf2f(hi)) : hi;
  }
  *(uint4*)&dst[(size_t)r*1536 + o*8] = packh8(h);
}

// Uh^T packed splits: phys [hi(512) | lo(512)]
__global__ void k_buhT(const float* __restrict__ Uh, u16* __restrict__ dst){
  int g = blockIdx.x*256 + threadIdx.x; if (g >= 2048*128) return;
  int pc = g/128, o = g%128; int oc = ocol(pc);
  u16 h[8];
  #pragma unroll
  for(int j=0;j<8;++j){
    int kp = o*8+j; int r = kp&511;
    float f = Uh[(size_t)r*2048 + oc];
    u16 hi = f2bf(f);
    h[j] = (kp<512) ? hi : f2bf(f - bf2f(hi));
  }
  *(uint4*)&dst[(size_t)pc*1024 + o*8] = packh8(h);
}

// (WzcT + Uh-on-top)^T splits: phys [hi(1536) | lo(1536)]
// wzcT is [2048 pc][1536 r]  (transposed composite) -> row-coalesced reads
__global__ void k_wzcT(const float* __restrict__ wzcT, const float* __restrict__ Uh, u16* __restrict__ dst){
  int g = blockIdx.x*256 + threadIdx.x; if (g >= 2048*384) return;
  int pc = g/384, o = g%384; int oc = ocol(pc);
  u16 h[8];
  #pragma unroll
  for(int j=0;j<8;++j){
    int kp = o*8+j; int r = kp % 1536;
    float f = wzcT[(size_t)pc*1536 + r] + ((r<512) ? Uh[(size_t)r*2048 + oc] : 0.f);
    u16 hi = f2bf(f);
    h[j] = (kp<1536) ? hi : f2bf(f - bf2f(hi));
  }
  *(uint4*)&dst[(size_t)pc*3072 + o*8] = packh8(h);
}

// A2cat = [h2 | ctx] bf16, rows r = t*64+b  (reads slot t+1 == row r+64)
__global__ void k_a2dump(const float* __restrict__ h2X, const float* __restrict__ ctxX, u16* __restrict__ dst){
  int g = blockIdx.x*256 + threadIdx.x; if (g >= 3776*192) return;
  int r = g/192, o = g%192;
  u16 h[8];
  #pragma unroll
  for(int j=0;j<8;++j){
    int k = o*8+j;
    float f = (k<512) ? h2X[(size_t)(r+64)*512 + k] : ctxX[(size_t)(r+64)*1024 + (k-512)];
    h[j] = f2bf(f);
  }
  *(uint4*)&dst[(size_t)r*1536 + o*8] = packh8(h);
}

// Wf [512][34004] f32 -> WfT [34004][512] bf16 (LDS-tiled transpose)
__global__ __launch_bounds__(256) void k_wfT(const float* __restrict__ Wf, u16* __restrict__ WfT){
  __shared__ u16 T[64*72];
  int n0 = blockIdx.x*64, k0 = blockIdx.y*64;
  int tid = threadIdx.x;
  int kl = tid>>2, nq = (tid&3)*16;
  u16 h[16];
  if (n0 + 64 <= 34004){
    const float4* p = (const float4*)(Wf + (size_t)(k0+kl)*34004 + n0 + nq);
    #pragma unroll
    for(int q=0;q<4;++q){ float4 f = p[q]; h[q*4+0]=f2bf(f.x); h[q*4+1]=f2bf(f.y); h[q*4+2]=f2bf(f.z); h[q*4+3]=f2bf(f.w); }
  } else {
    #pragma unroll
    for(int j=0;j<16;++j){ int n = n0+nq+j; float f = (n<34004)? Wf[(size_t)(k0+kl)*34004 + n] : 0.f; h[j]=f2bf(f); }
  }
  *(uint4*)&T[kl*72 + nq] = packh8(h);
  *(uint4*)&T[kl*72 + nq + 8] = packh8(h+8);
  __syncthreads();
  int nl = tid>>2, kq = (tid&3)*16;
  int n = n0 + nl;
  if (n < 34004){
    u16 o[16];
    #pragma unroll
    for(int j=0;j<16;++j) o[j] = T[(kq+j)*72 + nl];
    *(uint4*)&WfT[(size_t)n*512 + k0 + kq]     = packh8(o);
    *(uint4*)&WfT[(size_t)n*512 + k0 + kq + 8] = packh8(o+8);
  }
}

// ---------- generic 128x128 bf16 MFMA GEMM:  C[M,N] = A[M,K] * Bt[N,K]^T ----------
// EPI: 0 plain f32, 1 +bias f32, 2 bf16 out, 3 logits (bias + (t,b)->(b,t) permuted store)
// K-loop software-prefetches the next chunk's global loads so their latency overlaps
// the ds_read+MFMA of the current chunk.
// Epilogue stages each wave's 16x64 sub-tile through LDS and stores lane-contiguous
// float4 (256B per 16 lanes) -> full-line writes, no write-allocate RMW on HBM.
template<int EPI>
__global__ __launch_bounds__(256,2) void gemm_bf16(
    const u16* __restrict__ A, const u16* __restrict__ Bt,
    int M, int N, int K,
    float* __restrict__ Cf, u16* __restrict__ Cb,
    const float* __restrict__ bias, float* __restrict__ Cout){
  __shared__ u16 LSbuf[2*128*40];
  u16* Als = LSbuf;
  u16* Bls = LSbuf + 128*40;
  int tid = threadIdx.x;
  int c0 = blockIdx.x*128, r0 = blockIdx.y*128;
  int wid = tid>>6, wr = wid>>1, wc = wid&1;
  int l15 = tid&15, l4 = (tid>>4)&3;
  f4v acc[4][4];
  #pragma unroll
  for(int m=0;m<4;++m)
  #pragma unroll
  for(int n=0;n<4;++n)
  #pragma unroll
  for(int i=0;i<4;++i) acc[m][n][i] = 0.f;

  int r = tid>>1, hf = tid&1;
  size_t arow = (size_t)min(r0 + r, M-1);
  size_t brow = (size_t)min(c0 + r, N-1);
  const u16* abase = A  + arow*K + hf*16;
  const u16* bbase = Bt + brow*K + hf*16;
  int nk = K >> 5;
  uint4 a0 = ((const uint4*)abase)[0], a1 = ((const uint4*)abase)[1];
  uint4 b0 = ((const uint4*)bbase)[0], b1 = ((const uint4*)bbase)[1];
  for (int ch=0; ch<nk; ++ch){
    __syncthreads();
    *(uint4*)&Als[r*40 + hf*16]     = a0;
    *(uint4*)&Als[r*40 + hf*16 + 8] = a1;
    *(uint4*)&Bls[r*40 + hf*16]     = b0;
    *(uint4*)&Bls[r*40 + hf*16 + 8] = b1;
    __syncthreads();
    if (ch+1 < nk){
      const uint4* ap = (const uint4*)(abase + (ch+1)*32);
      const uint4* bp = (const uint4*)(bbase + (ch+1)*32);
      a0 = ap[0]; a1 = ap[1]; b0 = bp[0]; b1 = bp[1];
    }
    s8v af[4], bfr[4];
    #pragma unroll
    for(int m=0;m<4;++m) af[m]  = *(const s8v*)&Als[(wr*64 + m*16 + l15)*40 + l4*8];
    #pragma unroll
    for(int n=0;n<4;++n) bfr[n] = *(const s8v*)&Bls[(wc*64 + n*16 + l15)*40 + l4*8];
    #pragma unroll
    for(int m=0;m<4;++m)
    #pragma unroll
    for(int n=0;n<4;++n)
      acc[m][n] = __builtin_amdgcn_mfma_f32_16x16x32_bf16(af[m], bfr[n], acc[m][n], 0,0,0);
  }
  // epilogue: LDS-staged transpose to full-line float4 stores
  __syncthreads();   // all waves done reading Als/Bls before reuse
  float* eps = ((float*)LSbuf) + wid*1024;   // 16 rows x 64 cols per wave
  #pragma unroll
  for(int m=0;m<4;++m){
    #pragma unroll
    for(int n=0;n<4;++n)
    #pragma unroll
    for(int i=0;i<4;++i)
      eps[(l4*4 + i)*64 + n*16 + l15] = acc[m][n][i];
    // per-wave region: in-order LDS ops within a wave, no __syncthreads needed
    #pragma unroll
    for(int q=0;q<4;++q){
      int row = l4 + q*4;
      f4v v = *(const f4v*)&eps[row*64 + l15*4];
      int gr = r0 + wr*64 + m*16 + row;
      int gc = c0 + wc*64 + l15*4;
      if (gr < M && gc < N){
        if constexpr (EPI==0){
          *(f4v*)&Cf[(size_t)gr*N + gc] = v;
        } else if constexpr (EPI==1){
          f4v bv = *(const f4v*)&bias[gc];
          v += bv;
          *(f4v*)&Cf[(size_t)gr*N + gc] = v;
        } else if constexpr (EPI==2){
          unsigned p0 = ((unsigned)f2bf(v[1])<<16) | f2bf(v[0]);
          unsigned p1 = ((unsigned)f2bf(v[3])<<16) | f2bf(v[2]);
          uint2 pk; pk.x = p0; pk.y = p1;
          *(uint2*)&Cb[(size_t)gr*N + gc] = pk;
        } else {
          f4v bv = *(const f4v*)&bias[gc];
          v += bv;
          int b_ = gr&63, tt = gr>>6;
          *(f4v*)&Cout[((size_t)(b_*59 + tt))*34004 + gc] = v;
        }
      }
    }
  }
}

// ---------- per-step z-GEMM: 4 waves/block, each wave a 128-K sub-slice; LDS reduce ----------
// 64 col-blocks x (3|9) k-slices = (192|576) blocks -> ~2300 waves for TLP.
// A comes pre-split as bf16 hi/lo hcat[64][1536] (h:0..511, ctx:512..1535).
// variant 0 (t==0): virtual K=1536 over h only [Ahi*Bhi | Alo*Bhi | Ahi*Blo], Bt=buhT physK=1024
// variant 1 (t>=1): virtual K=4608 [hi*hi | lo*hi | hi*lo] over 1536,     Bt=wzT physK=3072
// Output store remaps packed col pc -> gate-contiguous slot for float4 LSTM reads.
struct SBuf2 { uint4 a[4]; uint4 b[2]; };

__global__ __launch_bounds__(256,2) void s1_zgemm(
    const u16* __restrict__ Bt, const u16* __restrict__ hhi, const u16* __restrict__ hlo,
    float* __restrict__ zparts, int physK, int variant){
  __shared__ float red[4][64*32];
  int tid = threadIdx.x;
  int wv = tid>>6, lane = tid&63;
  int l15 = lane&15, l4 = lane>>4;
  int pc0 = blockIdx.x*32;
  int kbase = blockIdx.y*512 + wv*128;
  f4v acc[4][2];
  #pragma unroll
  for(int m=0;m<4;++m)
  #pragma unroll
  for(int n=0;n<2;++n)
  #pragma unroll
  for(int i=0;i<4;++i) acc[m][n][i] = 0.f;

  SBuf2 B0, B1;
  auto loadc = [&](SBuf2& bu, int ch){
    int k1 = kbase + ch*32;
    const u16* ap; int inner;
    if (variant==0){ inner = k1 & 511; ap = ((((k1>>9)&3)==1) ? hlo : hhi); }
    else { int sg = k1/1536; inner = k1 - sg*1536; ap = ((sg==1) ? hlo : hhi); }
    #pragma unroll
    for(int m=0;m<4;++m)
      bu.a[m] = *(const uint4*)(ap + (size_t)(m*16 + l15)*1536 + inner + l4*8);
    int kB = (variant==0) ? ((k1 < 1024) ? (k1 & 511) : (k1 - 512))
                          : ((k1 < 3072) ? (k1 % 1536) : (1536 + (k1 - 3072)));
    #pragma unroll
    for(int n=0;n<2;++n)
      bu.b[n] = *(const uint4*)(Bt + (size_t)(pc0 + n*16 + l15)*physK + kB + l4*8);
  };
  auto proc = [&](SBuf2& bu){
    #pragma unroll
    for(int m=0;m<4;++m){
      s8v am = u4s8(bu.a[m]);
      #pragma unroll
      for(int n=0;n<2;++n)
        acc[m][n] = __builtin_amdgcn_mfma_f32_16x16x32_bf16(am, u4s8(bu.b[n]), acc[m][n], 0,0,0);
    }
  };

  loadc(B0, 0); loadc(B1, 1);
  proc(B0);     loadc(B0, 2);
  proc(B1);     loadc(B1, 3);
  proc(B0);
  proc(B1);

  #pragma unroll
  for(int m=0;m<4;++m)
  #pragma unroll
  for(int n=0;n<2;++n)
  #pragma unroll
  for(int i=0;i<4;++i)
    red[wv][(m*16 + l4*4 + i)*32 + n*16 + l15] = acc[m][n][i];
  __syncthreads();

  int rr = tid>>2, cq = (tid&3)*8;
  float* zp = zparts + (size_t)blockIdx.y*131072 + (size_t)rr*2048;
  #pragma unroll
  for(int k=0;k<2;++k){
    f4v s = *(const f4v*)&red[0][rr*32 + cq + k*4];
    #pragma unroll
    for(int w=1;w<4;++w)
      s += *(const f4v*)&red[w][rr*32 + cq + k*4];
    #pragma unroll
    for(int e=0;e<4;++e){
      int pc = pc0 + cq + k*4 + e;
      int slot = (pc & ~31) | ((pc&7)<<2) | ((pc>>3)&3);
      zp[slot] = s[e];
    }
  }
}

// ---------- per-step fused: LSTM + q + scores/softmax + ctx  (one block per batch b) ----------
__global__ __launch_bounds__(512) void s2b_fused(
    const float* __restrict__ zparts, int nsl, const float* __restrict__ ZembT,
    float* __restrict__ cst, float* __restrict__ h2out, float* __restrict__ ctxout,
    const u16* __restrict__ Wqb, const float* __restrict__ keys,
    const float* __restrict__ enc, const float* __restrict__ vv,
    u16* __restrict__ hhi, u16* __restrict__ hlo){
  __shared__ float h2s[512], vs2[512], qs[512];
  __shared__ float qp_l[8*512];
  __shared__ float scl[32], all[32];
  int b = blockIdx.x, tid = threadIdx.x;

  // (a) LSTM for unit j = tid (gate-contiguous slot layout -> float4 loads)
  {
    int j = tid;
    int base = (j>>3)*32 + (j&7)*4;            // slots for gates i,f,g,o of unit j
    f4v s4 = *(const f4v*)&ZembT[(size_t)b*2048 + base];
    for(int sl=0; sl<nsl; ++sl)
      s4 += *(const f4v*)&zparts[(size_t)sl*131072 + (size_t)b*2048 + base];
    float cprev = cst[(size_t)b*512 + j];
    float c2 = sigm(s4[1])*cprev + sigm(s4[0])*tanhx(s4[2]);
    float h2 = sigm(s4[3])*tanhx(c2);
    cst[(size_t)b*512 + j] = c2;
    h2out[(size_t)b*512 + j] = h2;
    h2s[j] = h2; vs2[j] = vv[j];
    u16 hh = f2bf(h2);
    hhi[(size_t)b*1536 + j] = hh;
    hlo[(size_t)b*1536 + j] = f2bf(h2 - bf2f(hh));
  }
  __syncthreads();
  // (c) q = h2 @ Wq  (Wq kept natural [h][c], bf16): thread -> 8 cols, 1/8 of h
  {
    int c8 = (tid&63)*8, hs = tid>>6;
    float qp[8] = {0,0,0,0,0,0,0,0};
    for(int hh=0; hh<64; ++hh){
      int h = hs*64 + hh;
      float w[8]; unp8(*(const uint4*)(Wqb + (size_t)h*512 + c8), w);
      float hv = h2s[h];
      #pragma unroll
      for(int j=0;j<8;++j) qp[j] += hv*w[j];
    }
    *(float4*)&qp_l[hs*512 + c8]     = make_float4(qp[0],qp[1],qp[2],qp[3]);
    *(float4*)&qp_l[hs*512 + c8 + 4] = make_float4(qp[4],qp[5],qp[6],qp[7]);
  }
  __syncthreads();
  { float s = 0.f; for(int hs=0; hs<8; ++hs) s += qp_l[hs*512 + tid]; qs[tid] = s; }
  __syncthreads();
  // (e) scores[s] = sum_h v[h]*tanh(keys[b,s,h] + q[h]) ; 16 threads per s, float4 keys
  {
    int s = tid>>4, hh = tid&15;
    const float4* kb4 = (const float4*)(keys + ((size_t)(b*32 + s))*512 + hh*32);
    float part = 0.f;
    #pragma unroll
    for(int i8=0;i8<8;++i8){
      float4 kv = kb4[i8];
      int h = hh*32 + i8*4;
      part += vs2[h+0]*tanhx(kv.x + qs[h+0]);
      part += vs2[h+1]*tanhx(kv.y + qs[h+1]);
      part += vs2[h+2]*tanhx(kv.z + qs[h+2]);
      part += vs2[h+3]*tanhx(kv.w + qs[h+3]);
    }
    #pragma unroll
    for(int m=1;m<16;m<<=1) part += __shfl_xor(part, m, 64);
    if (hh==0) scl[s] = part;
  }
  __syncthreads();
  // (g) softmax over 32
  if (tid < 32){
    float sc = scl[tid];
    float mx = sc;
    #pragma unroll
    for(int m=1;m<32;m<<=1) mx = fmaxf(mx, __shfl_xor(mx, m, 64));
    float e = __expf(sc - mx);
    float sm = e;
    #pragma unroll
    for(int m=1;m<32;m<<=1) sm += __shfl_xor(sm, m, 64);
    all[tid] = e/sm;
  }
  __syncthreads();
  // (i) ctx[m] = sum_s align[s]*enc[b,s,m] ; 2 adjacent cols per thread (float2)
  {
    const float* eb = enc + (size_t)b*32*1024;
    int cc = tid*2;
    float c0 = 0.f, c1 = 0.f;
    for(int s=0;s<32;++s){
      float al = all[s];
      float2 e2 = *(const float2*)&eb[(size_t)s*1024 + cc];
      c0 += al*e2.x;
      c1 += al*e2.y;
    }
    float2 co; co.x = c0; co.y = c1;
    *(float2*)&ctxout[(size_t)b*1024 + cc] = co;
    u16 x0 = f2bf(c0), x1 = f2bf(c1);
    *(unsigned*)&hhi[(size_t)b*1536 + 512 + cc] = (unsigned)x0 | ((unsigned)x1<<16);
    u16 y0 = f2bf(c0 - bf2f(x0)), y1 = f2bf(c1 - bf2f(x1));
    *(unsigned*)&hlo[(size_t)b*1536 + 512 + cc] = (unsigned)y0 | ((unsigned)y1<<16);
  }
}

// ---------- host ----------
extern "C" void kernel_launch(void* const* d_in, const int* in_sizes, int n_in,
                              void* d_out, int out_size, void* d_ws, size_t ws_size,
                              hipStream_t stream){
  const int*   dec = (const int*)d_in[0];
  const float* enc = (const float*)d_in[1];
  const float* eh  = (const float*)d_in[2];
  const float* ec  = (const float*)d_in[3];
  const float* emb = (const float*)d_in[4];
  const float* Wx  = (const float*)d_in[5];
  const float* Uh  = (const float*)d_in[6];
  const float* bb  = (const float*)d_in[7];
  const float* Wm  = (const float*)d_in[8];
  const float* Wq  = (const float*)d_in[9];
  const float* vv  = (const float*)d_in[10];
  const float* Wa  = (const float*)d_in[11];
  const float* Wf  = (const float*)d_in[12];
  const float* bf  = (const float*)d_in[13];
  float* out = (float*)d_out;

  // ---- workspace carving ----
  char* w = (char*)d_ws; size_t off = 0;
  auto alloc = [&](size_t bytes)->char*{ char* p = w + off; off = (off + bytes + 255) & ~(size_t)255; return p; };
  // live-at-final-GEMM group (must be in ws):
  u16* WfT   = (u16*)alloc((size_t)34004*512*2);
  u16* attn2 = (u16*)alloc((size_t)3776*512*2);
  size_t liveEnd = off;
  const size_t needB = (size_t)130<<20;
  bool fits = (ws_size >= liveEnd + needB);
  char* wb = fits ? (w + liveEnd) : (char*)d_out;   // d_out region is dead until final GEMM writes it
  size_t offb = 0;
  auto allocB = [&](size_t bytes)->char*{ char* p = wb + offb; offb = (offb + bytes + 255) & ~(size_t)255; return p; };

  u16* wzT   = (u16*)allocB((size_t)2048*3072*2);
  u16* buhT  = (u16*)allocB((size_t)2048*1024*2);
  u16* wqB   = (u16*)allocB((size_t)512*512*2);
  u16* waT   = (u16*)allocB((size_t)512*1536*2);
  u16* wmT   = (u16*)allocB((size_t)512*1024*2);
  u16* wxtpT = (u16*)allocB((size_t)2048*320*2);
  u16* wxaT  = (u16*)allocB((size_t)2048*1536*2);
  u16* waA   = (u16*)allocB((size_t)1536*1536*2);
  float* wzc = (float*)allocB((size_t)2048*1536*4);   // holds WzcT [2048][1536]
  u16* embB  = (u16*)allocB((size_t)3776*320*2);
  u16* encB  = (u16*)allocB((size_t)2048*1024*2);
  float* Zemb  = (float*)allocB((size_t)3776*2048*4);
  float* keys  = (float*)allocB((size_t)2048*512*4);
  float* zparts= (float*)allocB((size_t)9*64*2048*4);
  float* h2X   = (float*)allocB((size_t)60*64*512*4);
  float* ctxX  = (float*)allocB((size_t)60*64*1024*4);
  float* cst   = (float*)allocB((size_t)64*512*4);
  float* bp    = (float*)allocB((size_t)2048*4);
  u16* A2c   = (u16*)allocB((size_t)3776*1536*2);
  u16* hhi   = (u16*)allocB((size_t)64*1536*2);
  u16* hlo   = (u16*)allocB((size_t)64*1536*2);

  // ---- precompute ----
  k_init<<<520,256,0,stream>>>(bb, eh, ec, bp, h2X, cst, ctxX);
  k_hinit<<<384,256,0,stream>>>(eh, hhi, hlo);
  k_embgather<<<(3776*40+255)/256,256,0,stream>>>(dec, emb, embB);
  k_cvt<<<(262144+255)/256,256,0,stream>>>(enc, encB, 262144);          // enc -> bf16
  k_cvt<<<(32768+255)/256,256,0,stream>>>(Wq, wqB, 32768);              // Wq -> bf16 (natural layout)
  k_wmT<<<(512*128+255)/256,256,0,stream>>>(Wm, wmT);
  k_waT<<<(512*192+255)/256,256,0,stream>>>(Wa, waT);
  k_wxtpT<<<(2048*40+255)/256,256,0,stream>>>(Wx, wxtpT);
  k_wxaT<<<(2048*192+255)/256,256,0,stream>>>(Wx, wxaT);
  k_buhT<<<(2048*128+255)/256,256,0,stream>>>(Uh, buhT);
  k_waA<<<(1536*192+255)/256,256,0,stream>>>(Wa, waA);
  k_wfT<<<dim3(532,8),256,0,stream>>>(Wf, WfT);

  // Zemb = gather(emb) @ Wx_top (slot cols) + b   [3776][2048]
  gemm_bf16<1><<<dim3(16,30),256,0,stream>>>(embB, wxtpT, 3776, 2048, 320, Zemb, nullptr, bp, nullptr);
  // keys = enc @ Wm  [2048][512]
  gemm_bf16<0><<<dim3(4,16),256,0,stream>>>(encB, wmT, 2048, 512, 1024, keys, nullptr, nullptr, nullptr);
  // WzcT = Wx_att^T @ Wa^T (transposed composite, split-precision)  [2048 pc][1536 r]
  gemm_bf16<0><<<dim3(12,16),256,0,stream>>>(wxaT, waA, 2048, 1536, 1536, wzc, nullptr, nullptr, nullptr);
  // W'z^T = split( WzcT + Uh(top) )^T   [2048][3072]
  k_wzcT<<<(2048*384+255)/256,256,0,stream>>>(wzc, Uh, wzT);

  // ---- recurrence: 2 kernels per step ----
  for (int t=0; t<59; ++t){
    if (t==0){
      s1_zgemm<<<dim3(64,3),256,0,stream>>>(buhT, hhi, hlo, zparts, 1024, 0);
    } else {
      s1_zgemm<<<dim3(64,9),256,0,stream>>>(wzT, hhi, hlo, zparts, 3072, 1);
    }
    int nsl = (t==0) ? 3 : 9;
    s2b_fused<<<64,512,0,stream>>>(zparts, nsl, Zemb + (size_t)t*131072,
                                   cst, h2X + (size_t)(t+1)*32768, ctxX + (size_t)(t+1)*65536,
                                   wqB, keys, enc, vv, hhi, hlo);
  }

  // ---- deferred attn2 + logits ----
  k_a2dump<<<(3776*192+255)/256,256,0,stream>>>(h2X, ctxX, A2c);
  // attn2 = [h2|ctx] @ Wa  -> bf16 [3776][512]
  gemm_bf16<2><<<dim3(4,30),256,0,stream>>>(A2c, waT, 3776, 512, 1536, nullptr, attn2, nullptr, nullptr);
  // logits = attn2 @ Wf + bf, stored as out[b][t][v]
  gemm_bf16<3><<<dim3(266,30),256,0,stream>>>(attn2, WfT, 3776, 34004, 512, nullptr, nullptr, bf, out);
}